// Round 8
// baseline (408.586 us; speedup 1.0000x reference)
//
#include <hip/hip_runtime.h>
#include <stdint.h>

#define NB 2
#define NH 16
#define SEQ 4096
#define DD 64
#define QBLK 128        // queries per block (4 waves x 32q)
#define TKEY 64         // keys per LDS tile

typedef __attribute__((ext_vector_type(8)))  __bf16 bf16x8;
typedef __attribute__((ext_vector_type(16))) float  f32x16;
typedef __attribute__((ext_vector_type(2)))  unsigned int u32x2;

static __device__ __forceinline__ f32x16 zero16() {
    f32x16 z;
#pragma unroll
    for (int i = 0; i < 16; i++) z[i] = 0.0f;
    return z;
}

// (256,4): 4 blocks/CU (16 waves) under either launch_bounds semantics -> 128 VGPR cap.
__global__ void __launch_bounds__(256, 4)
swa_kernel(const float* __restrict__ Q, const float* __restrict__ K,
           const float* __restrict__ V, const float* __restrict__ scale_p,
           float* __restrict__ out)
{
    // XCD swizzle: 1024 blocks, %8==0 -> bijective; consecutive lid = same bh,
    // neighboring mq -> shared K/V chunks within one XCD's L2.
    int b = (int)blockIdx.x;
    int lid = (b & 7) * 128 + (b >> 3);
    const int mq = lid & 31;        // 128-q block within head
    const int bh = lid >> 5;        // b*NH + h
    const int m  = mq >> 1;         // 256-row window block

    const float scale = scale_p[0];
    const float* Qb = Q + (size_t)bh * SEQ * DD;
    const float* Kb = K + (size_t)bh * SEQ * DD;
    const float* Vb = V + (size_t)bh * SEQ * DD;
    float*       Ob = out + (size_t)bh * SEQ * DD;

    const int tid  = threadIdx.x;
    const int lane = tid & 63;
    const int qt   = tid >> 6;      // wave 0..3
    const int l31  = lane & 31;
    const int h5   = lane >> 5;

    // K tile, fragment-major: [kt(2)][s(4)][lane(64)][16B] = 8 KB, conflict-free b128.
    __shared__ __align__(16) unsigned char kl[8192];
    // V^T tile: [d(64)][key(64)*2B = 128B row], XOR-swizzled slot = (d&7)^(d>>3).
    __shared__ __align__(16) unsigned char vl[8192];

    // ---- Q fragments (B operand of swapped QK^T), prescaled.
    bf16x8 qf[4];
    {
        const float* qp = Qb + (size_t)(mq * QBLK + qt * 32 + l31) * DD + 8 * h5;
#pragma unroll
        for (int s = 0; s < 4; s++) {
            float4 a = *(const float4*)(qp + 16 * s);
            float4 c = *(const float4*)(qp + 16 * s + 4);
            bf16x8 f;
            f[0] = (__bf16)(a.x * scale); f[1] = (__bf16)(a.y * scale);
            f[2] = (__bf16)(a.z * scale); f[3] = (__bf16)(a.w * scale);
            f[4] = (__bf16)(c.x * scale); f[5] = (__bf16)(c.y * scale);
            f[6] = (__bf16)(c.z * scale); f[7] = (__bf16)(c.w * scale);
            qf[s] = f;
        }
    }

    f32x16 accA0 = zero16(), accA1 = zero16();
    f32x16 accB0 = zero16(), accB1 = zero16();
    float dA = 0.0f, dB = 0.0f;

    const int c0 = (m > 0) ? m - 1 : 0;
    const int c1 = (m < 15) ? m + 1 : 15;

    const int skey = tid >> 2;      // 0..63 staging key
    const int sdp  = tid & 3;       // 0..3  staging d-quarter (16 floats)

    for (int c = c0; c <= c1; ++c) {
        const int rel = c - m + 1;              // 0,1,2
        const bool inA = (m > 0) && (rel <= 1); // window A: chunks m-1, m
        const bool inB = (rel >= 1);            // window B: chunks m, m+1 (m=15: c1 clamp)

        for (int tt = 0; tt < 4; ++tt) {
            const int k0 = c * 256 + tt * TKEY;
            __syncthreads();
            // ---- stage K 64-key tile -> LDS fragment-major bf16 (coalesced 64B/thread)
            {
                const float* kp = Kb + (size_t)(k0 + skey) * DD + sdp * 16;
                float4 f0 = *(const float4*)(kp);
                float4 f1 = *(const float4*)(kp + 4);
                float4 f2 = *(const float4*)(kp + 8);
                float4 f3 = *(const float4*)(kp + 12);
                bf16x8 o0, o1;
                o0[0] = (__bf16)f0.x; o0[1] = (__bf16)f0.y; o0[2] = (__bf16)f0.z; o0[3] = (__bf16)f0.w;
                o0[4] = (__bf16)f1.x; o0[5] = (__bf16)f1.y; o0[6] = (__bf16)f1.z; o0[7] = (__bf16)f1.w;
                o1[0] = (__bf16)f2.x; o1[1] = (__bf16)f2.y; o1[2] = (__bf16)f2.z; o1[3] = (__bf16)f2.w;
                o1[4] = (__bf16)f3.x; o1[5] = (__bf16)f3.y; o1[6] = (__bf16)f3.z; o1[7] = (__bf16)f3.w;
                unsigned char* base = kl + (skey >> 5) * 4096 + sdp * 1024 + (skey & 31) * 16;
                *(bf16x8*)(base)       = o0;   // h=0 (d 16sdp+0..7)
                *(bf16x8*)(base + 512) = o1;   // h=1 (d 16sdp+8..15)
            }
            // ---- stage V^T 64-key tile -> LDS (transpose, b16 writes, 2-way max)
            {
                const float* vp = Vb + (size_t)(k0 + skey) * DD + sdp * 16;
                float4 g0 = *(const float4*)(vp);
                float4 g1 = *(const float4*)(vp + 4);
                float4 g2 = *(const float4*)(vp + 8);
                float4 g3 = *(const float4*)(vp + 12);
                float va[16] = {g0.x, g0.y, g0.z, g0.w, g1.x, g1.y, g1.z, g1.w,
                                g2.x, g2.y, g2.z, g2.w, g3.x, g3.y, g3.z, g3.w};
#pragma unroll
                for (int e = 0; e < 16; ++e) {
                    const int d = sdp * 16 + e;
                    const int swz = ((d & 7) ^ (d >> 3)) << 4;
                    *(__bf16*)(vl + d * 128 + ((skey * 2) ^ swz)) = (__bf16)va[e];
                }
            }
            __syncthreads();

            // ---- compute: 2 key sub-tiles of 32
#pragma unroll
            for (int kt = 0; kt < 2; ++kt) {
                const unsigned char* kfb = kl + kt * 4096 + lane * 16;
                f32x16 st = zero16();
#pragma unroll
                for (int s = 0; s < 4; s++) {
                    bf16x8 kf = *(const bf16x8*)(kfb + s * 1024);
                    st = __builtin_amdgcn_mfma_f32_32x32x16_bf16(kf, qf[s], st, 0, 0, 0);
                }
                // st: col(l31)=q, row=(r&3)+8*(r>>2)+4*h5 = key (scaled)

                uint32_t wv[8];
                float dsum = 0.0f;
#pragma unroll
                for (int i = 0; i < 8; i++) {
                    float p0 = __builtin_amdgcn_rcpf(1.0f + __expf(-st[2 * i]));
                    float p1 = __builtin_amdgcn_rcpf(1.0f + __expf(-st[2 * i + 1]));
                    dsum += p0 + p1;
                    union { __bf16 h[2]; uint32_t u; } pk;
                    pk.h[0] = (__bf16)p0;
                    pk.h[1] = (__bf16)p1;
                    wv[i] = pk.u;
                }
                if (inA) dA += dsum;
                if (inB) dB += dsum;

                // P relayout via permlane32_swap: ret[0]={x.lo|y.lo}, ret[1]={x.hi|y.hi}
                u32x2 rA = __builtin_amdgcn_permlane32_swap(wv[0], wv[2], false, false);
                u32x2 rB = __builtin_amdgcn_permlane32_swap(wv[1], wv[3], false, false);
                u32x2 rC = __builtin_amdgcn_permlane32_swap(wv[4], wv[6], false, false);
                u32x2 rD = __builtin_amdgcn_permlane32_swap(wv[5], wv[7], false, false);
                union { uint32_t u[4]; bf16x8 v; } A0, A1;
                A0.u[0] = rA[0]; A0.u[1] = rB[0]; A0.u[2] = rA[1]; A0.u[3] = rB[1];
                A1.u[0] = rC[0]; A1.u[1] = rD[0]; A1.u[2] = rC[1]; A1.u[3] = rD[1];

                // V fragments (B operand), swizzled reads (even bank spread)
                const int x0 = (((l31 & 7) ^ (l31 >> 3)) << 4);
                const int x1 = x0 ^ 64;
                const int off = kt * 64 + h5 * 16;
                bf16x8 v00 = *(const bf16x8*)(vl + l31 * 128 + (off ^ x0));
                bf16x8 v01 = *(const bf16x8*)(vl + l31 * 128 + ((off + 32) ^ x0));
                bf16x8 v10 = *(const bf16x8*)(vl + (32 + l31) * 128 + (off ^ x1));
                bf16x8 v11 = *(const bf16x8*)(vl + (32 + l31) * 128 + ((off + 32) ^ x1));

                if (inA) {
                    accA0 = __builtin_amdgcn_mfma_f32_32x32x16_bf16(A0.v, v00, accA0, 0, 0, 0);
                    accA0 = __builtin_amdgcn_mfma_f32_32x32x16_bf16(A1.v, v01, accA0, 0, 0, 0);
                    accA1 = __builtin_amdgcn_mfma_f32_32x32x16_bf16(A0.v, v10, accA1, 0, 0, 0);
                    accA1 = __builtin_amdgcn_mfma_f32_32x32x16_bf16(A1.v, v11, accA1, 0, 0, 0);
                }
                if (inB) {
                    accB0 = __builtin_amdgcn_mfma_f32_32x32x16_bf16(A0.v, v00, accB0, 0, 0, 0);
                    accB0 = __builtin_amdgcn_mfma_f32_32x32x16_bf16(A1.v, v01, accB0, 0, 0, 0);
                    accB1 = __builtin_amdgcn_mfma_f32_32x32x16_bf16(A0.v, v10, accB1, 0, 0, 0);
                    accB1 = __builtin_amdgcn_mfma_f32_32x32x16_bf16(A1.v, v11, accB1, 0, 0, 0);
                }
            }
        }
    }

    // ---- epilogue
    const float dAt = dA + __shfl_xor(dA, 32, 64);
    const float dBt = dB + __shfl_xor(dB, 32, 64);
    const float invA = __builtin_amdgcn_rcpf(dAt);
    const float invB = __builtin_amdgcn_rcpf(dBt);

#pragma unroll
    for (int r = 0; r < 16; r++) {
        const int cr = (r & 3) + 8 * (r >> 2) + 4 * h5;   // q row in wave tile
        const int jw = (mq & 1) * 128 + qt * 32 + cr;     // row within 256-window
        const float ia = __shfl(invA, cr, 64);
        const float ib = __shfl(invB, cr, 64);
        float o0, o1;
        if (m == 0) {
            o0 = accB0[r] * ib;
            o1 = accB1[r] * ib;
        } else {
            const float alpha = (float)jw * (1.0f / 255.0f);
            o0 = (1.0f - alpha) * (accA0[r] * ia) + alpha * (accB0[r] * ib);
            o1 = (1.0f - alpha) * (accA1[r] * ia) + alpha * (accB1[r] * ib);
        }
        float* orow = Ob + (size_t)(mq * QBLK + qt * 32 + cr) * DD;
        orow[l31]      = o0;
        orow[32 + l31] = o1;
    }
}

extern "C" void kernel_launch(void* const* d_in, const int* in_sizes, int n_in,
                              void* d_out, int out_size, void* d_ws, size_t ws_size,
                              hipStream_t stream) {
    const float* Q = (const float*)d_in[0];
    const float* K = (const float*)d_in[1];
    const float* V = (const float*)d_in[2];
    const float* s = (const float*)d_in[3];
    float* out = (float*)d_out;
    dim3 grid(NB * NH * (SEQ / QBLK), 1, 1);   // 1024
    dim3 block(256, 1, 1);
    hipLaunchKernelGGL(swa_kernel, grid, block, 0, stream, Q, K, V, s, out);
}

// Round 9
// 193.462 us; speedup vs baseline: 2.1120x; 2.1120x over previous
//
#include <hip/hip_runtime.h>
#include <stdint.h>

#define NB 2
#define NH 16
#define SEQ 4096
#define DD 64
#define NM 16           // 256-row query blocks per head
#define QB 256
#define CH 256          // keys per chunk
#define VSTR 528        // V^T LDS row stride (bytes): 0 conflicts measured in round 2

typedef __attribute__((ext_vector_type(8)))  __bf16 bf16x8;
typedef __attribute__((ext_vector_type(16))) float  f32x16;
typedef __attribute__((ext_vector_type(2)))  unsigned int u32x2;

static __device__ __forceinline__ f32x16 zero16() {
    f32x16 z;
#pragma unroll
    for (int i = 0; i < 16; i++) z[i] = 0.0f;
    return z;
}

// ---- kernel 1: stream-convert K f32 -> bf16 into workspace (coalesced, once)
__global__ void __launch_bounds__(256)
cvt_k_kernel(const float* __restrict__ K, __bf16* __restrict__ kw)
{
    const size_t gid = (size_t)blockIdx.x * 256 + threadIdx.x;
    const float* src = K + gid * 16;
    float4 a = *(const float4*)(src);
    float4 b = *(const float4*)(src + 4);
    float4 c = *(const float4*)(src + 8);
    float4 d = *(const float4*)(src + 12);
    bf16x8 o0, o1;
    o0[0] = (__bf16)a.x; o0[1] = (__bf16)a.y; o0[2] = (__bf16)a.z; o0[3] = (__bf16)a.w;
    o0[4] = (__bf16)b.x; o0[5] = (__bf16)b.y; o0[6] = (__bf16)b.z; o0[7] = (__bf16)b.w;
    o1[0] = (__bf16)c.x; o1[1] = (__bf16)c.y; o1[2] = (__bf16)c.z; o1[3] = (__bf16)c.w;
    o1[4] = (__bf16)d.x; o1[5] = (__bf16)d.y; o1[6] = (__bf16)d.z; o1[7] = (__bf16)d.w;
    *(bf16x8*)(kw + gid * 16)     = o0;
    *(bf16x8*)(kw + gid * 16 + 8) = o1;
}

// ---- kernel 2: attention. PRE=true: K from pre-converted bf16 ws (+prefetch).
// PRE=false: round-2 exact fallback (f32 K load + inline cvt).
// launch_bounds (512,2) is the ONLY config measured not to spill (VGPR=128;
// rounds 5/8 proved any tighter bound caps VGPR at 64 -> acc spill -> 6x slower).
template<bool PRE>
__global__ void __launch_bounds__(512, 2)
swa_kernel(const float* __restrict__ Q, const float* __restrict__ K,
           const float* __restrict__ V, const float* __restrict__ scale_p,
           const __bf16* __restrict__ kw, float* __restrict__ out)
{
    // XCD-aware swizzle: consecutive resident blocks on an XCD share K/V chunks.
    int lid = (int)blockIdx.x;
    lid = (lid & 7) * 64 + (lid >> 3);
    const int m  = lid & 15;        // query block
    const int bh = lid >> 4;        // b*NH + h

    const float scale = scale_p[0];     // 0.125 exactly -> folding into Q is exact
    const float* Qb = Q + (size_t)bh * SEQ * DD;
    const float* Kb = K + (size_t)bh * SEQ * DD;
    const float* Vb = V + (size_t)bh * SEQ * DD;
    const __bf16* kwb = kw + (size_t)bh * SEQ * DD;
    float*       Ob = out + (size_t)bh * SEQ * DD;

    const int tid  = threadIdx.x;
    const int lane = tid & 63;
    const int w    = tid >> 6;      // wave 0..7
    const int l31  = lane & 31;
    const int h5   = lane >> 5;

    __shared__ __align__(16) unsigned char vt[64 * VSTR];   // V^T chunk [d=64][key=256] bf16

    // ---- Q fragments (B operand of swapped QK^T), prescaled by `scale`
    bf16x8 qf[4];
    {
        const float* qp = Qb + (size_t)(m * QB + w * 32 + l31) * DD + 8 * h5;
#pragma unroll
        for (int s = 0; s < 4; s++) {
            float4 a = *(const float4*)(qp + 16 * s);
            float4 b = *(const float4*)(qp + 16 * s + 4);
            bf16x8 f;
            f[0] = (__bf16)(a.x * scale); f[1] = (__bf16)(a.y * scale);
            f[2] = (__bf16)(a.z * scale); f[3] = (__bf16)(a.w * scale);
            f[4] = (__bf16)(b.x * scale); f[5] = (__bf16)(b.y * scale);
            f[6] = (__bf16)(b.z * scale); f[7] = (__bf16)(b.w * scale);
            qf[s] = f;
        }
    }

    f32x16 accA0 = zero16(), accA1 = zero16();   // window A numerator
    f32x16 accB0 = zero16(), accB1 = zero16();   // window B numerator
    float dA = 0.0f, dB = 0.0f;

    for (int ci = 0; ci < 3; ci++) {
        const int ck = (m - 1 + ci) * CH;
        if (ck < 0 || ck >= SEQ) continue;       // m block-uniform -> barrier-safe
        const bool inA = (m > 0) && (ci <= 1);
        const bool inB = (ci >= 1);

        __syncthreads();
        // ---- stage V^T chunk -> LDS bf16 (transpose; round-2 verified, 0 conflicts)
        {
            const int kk = (tid & 127) * 2;
            const int dg = tid >> 7;
            const float* vp0 = Vb + (size_t)(ck + kk) * DD + dg * 16;
            const float* vp1 = vp0 + DD;
#pragma unroll
            for (int j = 0; j < 16; j += 4) {
                float4 a = *(const float4*)(vp0 + j);
                float4 b = *(const float4*)(vp1 + j);
                float av[4] = {a.x, a.y, a.z, a.w};
                float bv[4] = {b.x, b.y, b.z, b.w};
#pragma unroll
                for (int e = 0; e < 4; e++) {
                    union { __bf16 h[2]; uint32_t u; } pk;
                    pk.h[0] = (__bf16)av[e];
                    pk.h[1] = (__bf16)bv[e];
                    *(uint32_t*)(vt + (size_t)(dg * 16 + j + e) * VSTR + kk * 2) = pk.u;
                }
            }
        }

        bf16x8 kcur[4];
        if (PRE) {
            const __bf16* p = kwb + (size_t)(ck + l31) * DD + 8 * h5;
#pragma unroll
            for (int s = 0; s < 4; s++) kcur[s] = *(const bf16x8*)(p + 16 * s);
        }
        __syncthreads();

        // ---- 8 key tiles of 32
#pragma unroll 2
        for (int kt = 0; kt < 8; kt++) {
            f32x16 st = zero16();
            bf16x8 knx[4];
            if (PRE) {
                if (kt < 7) {   // prefetch next tile while computing this one
                    const __bf16* p = kwb + (size_t)(ck + (kt + 1) * 32 + l31) * DD + 8 * h5;
#pragma unroll
                    for (int s = 0; s < 4; s++) knx[s] = *(const bf16x8*)(p + 16 * s);
                }
#pragma unroll
                for (int s = 0; s < 4; s++)
                    st = __builtin_amdgcn_mfma_f32_32x32x16_bf16(kcur[s], qf[s], st, 0, 0, 0);
            } else {
                const float* kp = Kb + (size_t)(ck + kt * 32 + l31) * DD + 8 * h5;
#pragma unroll
                for (int s = 0; s < 4; s++) {
                    float4 a = *(const float4*)(kp + 16 * s);
                    float4 b = *(const float4*)(kp + 16 * s + 4);
                    bf16x8 f;
                    f[0] = (__bf16)a.x; f[1] = (__bf16)a.y; f[2] = (__bf16)a.z; f[3] = (__bf16)a.w;
                    f[4] = (__bf16)b.x; f[5] = (__bf16)b.y; f[6] = (__bf16)b.z; f[7] = (__bf16)b.w;
                    st = __builtin_amdgcn_mfma_f32_32x32x16_bf16(f, qf[s], st, 0, 0, 0);
                }
            }
            // st: col(l31)=q, row=(r&3)+8*(r>>2)+4*h5 = key (scaled)

            // ---- sigmoid, bf16 round, per-lane denominator
            uint32_t wv[8];
            float dsum = 0.0f;
#pragma unroll
            for (int i = 0; i < 8; i++) {
                float p0 = __builtin_amdgcn_rcpf(1.0f + __expf(-st[2 * i]));
                float p1 = __builtin_amdgcn_rcpf(1.0f + __expf(-st[2 * i + 1]));
                dsum += p0 + p1;
                union { __bf16 h[2]; uint32_t u; } pk;
                pk.h[0] = (__bf16)p0;
                pk.h[1] = (__bf16)p1;
                wv[i] = pk.u;
            }
            if (inA) dA += dsum;
            if (inB) dB += dsum;

            // ---- P relayout via permlane32_swap: ret[0]={x.lo|y.lo}, ret[1]={x.hi|y.hi}
            u32x2 rA = __builtin_amdgcn_permlane32_swap(wv[0], wv[2], false, false);
            u32x2 rB = __builtin_amdgcn_permlane32_swap(wv[1], wv[3], false, false);
            u32x2 rC = __builtin_amdgcn_permlane32_swap(wv[4], wv[6], false, false);
            u32x2 rD = __builtin_amdgcn_permlane32_swap(wv[5], wv[7], false, false);
            union { uint32_t u[4]; bf16x8 v; } A0, A1;
            A0.u[0] = rA[0]; A0.u[1] = rB[0]; A0.u[2] = rA[1]; A0.u[3] = rB[1];
            A1.u[0] = rC[0]; A1.u[1] = rD[0]; A1.u[2] = rC[1]; A1.u[3] = rD[1];

            // ---- V fragments from LDS (B operand)
            const unsigned char* vrow0 = vt + (size_t)l31 * VSTR;
            const unsigned char* vrow1 = vt + (size_t)(32 + l31) * VSTR;
            const int ko = kt * 64 + h5 * 16;
            bf16x8 v00 = *(const bf16x8*)(vrow0 + ko);
            bf16x8 v01 = *(const bf16x8*)(vrow0 + ko + 32);
            bf16x8 v10 = *(const bf16x8*)(vrow1 + ko);
            bf16x8 v11 = *(const bf16x8*)(vrow1 + ko + 32);

            if (inA) {
                accA0 = __builtin_amdgcn_mfma_f32_32x32x16_bf16(A0.v, v00, accA0, 0, 0, 0);
                accA0 = __builtin_amdgcn_mfma_f32_32x32x16_bf16(A1.v, v01, accA0, 0, 0, 0);
                accA1 = __builtin_amdgcn_mfma_f32_32x32x16_bf16(A0.v, v10, accA1, 0, 0, 0);
                accA1 = __builtin_amdgcn_mfma_f32_32x32x16_bf16(A1.v, v11, accA1, 0, 0, 0);
            }
            if (inB) {
                accB0 = __builtin_amdgcn_mfma_f32_32x32x16_bf16(A0.v, v00, accB0, 0, 0, 0);
                accB0 = __builtin_amdgcn_mfma_f32_32x32x16_bf16(A1.v, v01, accB0, 0, 0, 0);
                accB1 = __builtin_amdgcn_mfma_f32_32x32x16_bf16(A0.v, v10, accB1, 0, 0, 0);
                accB1 = __builtin_amdgcn_mfma_f32_32x32x16_bf16(A1.v, v11, accB1, 0, 0, 0);
            }
            if (PRE) {
#pragma unroll
                for (int s = 0; s < 4; s++) kcur[s] = knx[s];
            }
        }
    }

    // ---- epilogue: combine denominators, normalize, blend, store
    const float dAt = dA + __shfl_xor(dA, 32, 64);
    const float dBt = dB + __shfl_xor(dB, 32, 64);
    const float invA = __builtin_amdgcn_rcpf(dAt);
    const float invB = __builtin_amdgcn_rcpf(dBt);

#pragma unroll
    for (int r = 0; r < 16; r++) {
        const int cr = (r & 3) + 8 * (r >> 2) + 4 * h5;
        const int j  = w * 32 + cr;
        const float ia = __shfl(invA, cr, 64);
        const float ib = __shfl(invB, cr, 64);
        float o0, o1;
        if (m == 0) {
            o0 = accB0[r] * ib;
            o1 = accB1[r] * ib;
        } else {
            const float alpha = (float)j * (1.0f / 255.0f);
            o0 = (1.0f - alpha) * (accA0[r] * ia) + alpha * (accB0[r] * ib);
            o1 = (1.0f - alpha) * (accA1[r] * ia) + alpha * (accB1[r] * ib);
        }
        float* orow = Ob + (size_t)(m * QB + j) * DD;
        orow[l31]      = o0;
        orow[32 + l31] = o1;
    }
}

extern "C" void kernel_launch(void* const* d_in, const int* in_sizes, int n_in,
                              void* d_out, int out_size, void* d_ws, size_t ws_size,
                              hipStream_t stream) {
    const float* Q = (const float*)d_in[0];
    const float* K = (const float*)d_in[1];
    const float* V = (const float*)d_in[2];
    const float* s = (const float*)d_in[3];
    float* out = (float*)d_out;

    const size_t kElems  = (size_t)NB * NH * SEQ * DD;         // 8.39M
    const size_t kBytes  = kElems * sizeof(__bf16);            // 16.8 MB
    dim3 grid(NB * NH * NM, 1, 1);                             // 512
    dim3 block(512, 1, 1);

    if (ws_size >= kBytes) {
        __bf16* kw = (__bf16*)d_ws;
        dim3 cg((unsigned)(kElems / 16 / 256), 1, 1);          // 2048 blocks
        hipLaunchKernelGGL(cvt_k_kernel, cg, dim3(256, 1, 1), 0, stream, K, kw);
        hipLaunchKernelGGL((swa_kernel<true>), grid, block, 0, stream, Q, K, V, s, kw, out);
    } else {
        hipLaunchKernelGGL((swa_kernel<false>), grid, block, 0, stream, Q, K, V, s,
                           (const __bf16*)nullptr, out);
    }
}

// Round 10
// 184.133 us; speedup vs baseline: 2.2190x; 1.0507x over previous
//
#include <hip/hip_runtime.h>
#include <stdint.h>

#define NB 2
#define NH 16
#define SEQ 4096
#define DD 64
#define NM 16           // 256-row query blocks per head
#define QB 256
#define CH 256          // keys per chunk
#define VSTR 528        // fallback V^T LDS row stride (round-2 verified, 0 conflicts)
#define VTS 144         // tile V^T LDS row stride: 9x16B -> 2-way max (free)

typedef __attribute__((ext_vector_type(8)))  __bf16 bf16x8;
typedef __attribute__((ext_vector_type(16))) float  f32x16;
typedef __attribute__((ext_vector_type(2)))  unsigned int u32x2;

static __device__ __forceinline__ f32x16 zero16() {
    f32x16 z;
#pragma unroll
    for (int i = 0; i < 16; i++) z[i] = 0.0f;
    return z;
}

// ---- cvt kernel 1: K f32 -> bf16, FRAGMENT-MAJOR 64-key tiles (LDS-ready).
// Per 64-key tile (8192 B): [sub(2)][s(4)][ (k31 + 32*h) ][16B], where for key g,
// d = 16s + 8h + e  (matches 32x32x16 A-fragment: lane k31+32h reads d=16s+8h5+e).
__global__ void __launch_bounds__(256)
cvt_k_kernel(const float* __restrict__ K, unsigned char* __restrict__ kw)
{
    const int t   = blockIdx.x * 256 + threadIdx.x;
    const int g   = t >> 2;         // global key index (over NB*NH*SEQ)
    const int sdp = t & 3;          // d-quarter (16 d)
    const float* src = K + (size_t)g * DD + sdp * 16;
    float4 a = *(const float4*)(src);
    float4 b = *(const float4*)(src + 4);
    float4 c = *(const float4*)(src + 8);
    float4 d = *(const float4*)(src + 12);
    bf16x8 o0, o1;
    o0[0] = (__bf16)a.x; o0[1] = (__bf16)a.y; o0[2] = (__bf16)a.z; o0[3] = (__bf16)a.w;
    o0[4] = (__bf16)b.x; o0[5] = (__bf16)b.y; o0[6] = (__bf16)b.z; o0[7] = (__bf16)b.w;
    o1[0] = (__bf16)c.x; o1[1] = (__bf16)c.y; o1[2] = (__bf16)c.z; o1[3] = (__bf16)c.w;
    o1[4] = (__bf16)d.x; o1[5] = (__bf16)d.y; o1[6] = (__bf16)d.z; o1[7] = (__bf16)d.w;
    const int sub = (g >> 5) & 1, k31 = g & 31;
    unsigned char* db = kw + (size_t)(g >> 6) * 8192 + (sub * 4 + sdp) * 1024;
    *(bf16x8*)(db + k31 * 16)        = o0;   // h=0 (d = 16*sdp + 0..7)
    *(bf16x8*)(db + (k31 + 32) * 16) = o1;   // h=1 (d = 16*sdp + 8..15)
}

// ---- cvt kernel 2: V f32 -> bf16 TRANSPOSED 64-key tiles (row-linear 128B).
// Per tile (8192 B): [d(64)][key(64)*2B]. LDS-transposed for coalesced output.
__global__ void __launch_bounds__(256)
cvt_v_kernel(const float* __restrict__ V, unsigned char* __restrict__ vw)
{
    __shared__ __align__(16) unsigned char vt[64 * VTS];
    const int tile = blockIdx.x;
    const int t    = threadIdx.x;
    const int kk   = t >> 2;        // key within tile
    const int sdp  = t & 3;
    const float* src = V + ((size_t)tile * 64 + kk) * DD + sdp * 16;
#pragma unroll
    for (int j = 0; j < 4; j++) {
        float4 f = *(const float4*)(src + 4 * j);
        float fv[4] = {f.x, f.y, f.z, f.w};
#pragma unroll
        for (int e = 0; e < 4; e++) {
            const int d = sdp * 16 + 4 * j + e;
            *(__bf16*)(vt + d * VTS + kk * 2) = (__bf16)fv[e];
        }
    }
    __syncthreads();
#pragma unroll
    for (int p = 0; p < 2; p++) {
        const int idx = p * 4096 + t * 16;
        const int d = idx >> 7, cb = idx & 127;
        bf16x8 r = *(const bf16x8*)(vt + d * VTS + cb);
        *(bf16x8*)(vw + (size_t)tile * 8192 + idx) = r;
    }
}

// ---- main kernel (PRE path): double-buffered 64-key tile pipeline from
// LDS-ready ws. launch_bounds (512,2): the only config measured not to spill.
__global__ void __launch_bounds__(512, 2)
swa_pre_kernel(const float* __restrict__ Q, const float* __restrict__ scale_p,
               const unsigned char* __restrict__ kw, const unsigned char* __restrict__ vw,
               float* __restrict__ out)
{
    int lid = (int)blockIdx.x;
    lid = (lid & 7) * 64 + (lid >> 3);      // XCD swizzle: same-bh neighbors share L2
    const int m  = lid & 15;
    const int bh = lid >> 4;

    const float scale = scale_p[0];
    const float* Qb = Q + (size_t)bh * SEQ * DD;
    const unsigned char* kwb = kw + (size_t)bh * (SEQ / 64) * 8192;
    const unsigned char* vwb = vw + (size_t)bh * (SEQ / 64) * 8192;
    float* Ob = out + (size_t)bh * SEQ * DD;

    const int tid  = threadIdx.x;
    const int lane = tid & 63;
    const int w    = tid >> 6;
    const int l31  = lane & 31;
    const int h5   = lane >> 5;

    __shared__ __align__(16) unsigned char kbuf[2][8192];       // fragment-major K tile
    __shared__ __align__(16) unsigned char vbuf[2][64 * VTS];   // V^T tile, 144B rows

    // ---- Q fragments, prescaled (scale = 0.125 exact)
    bf16x8 qf[4];
    {
        const float* qp = Qb + (size_t)(m * QB + w * 32 + l31) * DD + 8 * h5;
#pragma unroll
        for (int s = 0; s < 4; s++) {
            float4 a = *(const float4*)(qp + 16 * s);
            float4 b = *(const float4*)(qp + 16 * s + 4);
            bf16x8 f;
            f[0] = (__bf16)(a.x * scale); f[1] = (__bf16)(a.y * scale);
            f[2] = (__bf16)(a.z * scale); f[3] = (__bf16)(a.w * scale);
            f[4] = (__bf16)(b.x * scale); f[5] = (__bf16)(b.y * scale);
            f[6] = (__bf16)(b.z * scale); f[7] = (__bf16)(b.w * scale);
            qf[s] = f;
        }
    }

    f32x16 accA0 = zero16(), accA1 = zero16();
    f32x16 accB0 = zero16(), accB1 = zero16();
    float dA = 0.0f, dB = 0.0f;

    const int c0 = (m > 0) ? m - 1 : 0;
    const int c1 = (m < 15) ? m + 1 : 15;
    const int T  = (c1 - c0 + 1) * 4;       // 64-key tiles (block-uniform)

    const int vdst = tid * 16 + (tid >> 3) * 16;   // = d*144 + c*16, d=tid>>3 c=tid&7

    // prologue: load tile 0 into regs
    bf16x8 g0, g1;
    {
        const size_t tb = (size_t)(c0 * 4) * 8192 + tid * 16;
        g0 = *(const bf16x8*)(kwb + tb);
        g1 = *(const bf16x8*)(vwb + tb);
    }

    for (int ti = 0; ti < T; ++ti) {
        const int c = c0 + (ti >> 2);
        const bool inA = (m > 0) && (c <= m);
        const bool inB = (c >= m);
        unsigned char* kb = kbuf[ti & 1];
        unsigned char* vb = vbuf[ti & 1];

        __syncthreads();                     // buf[ti&1] free (compute ti-2 done)
        *(bf16x8*)(kb + tid * 16) = g0;      // write tile ti (loads long complete)
        *(bf16x8*)(vb + vdst)     = g1;
        if (ti + 1 < T) {                    // issue next-tile loads; land during compute
            const size_t tb = (size_t)((c0 + ((ti + 1) >> 2)) * 4 + ((ti + 1) & 3)) * 8192
                              + tid * 16;
            g0 = *(const bf16x8*)(kwb + tb);
            g1 = *(const bf16x8*)(vwb + tb);
        }
        __syncthreads();                     // tile ti staged

#pragma unroll
        for (int kt = 0; kt < 2; ++kt) {
            f32x16 st = zero16();
#pragma unroll
            for (int s = 0; s < 4; s++) {
                bf16x8 kf = *(const bf16x8*)(kb + (kt * 4 + s) * 1024 + lane * 16);
                st = __builtin_amdgcn_mfma_f32_32x32x16_bf16(kf, qf[s], st, 0, 0, 0);
            }
            // st: col(l31)=q, row=(r&3)+8*(r>>2)+4*h5 = key (scaled)

            uint32_t wv[8];
            float dsum = 0.0f;
#pragma unroll
            for (int i = 0; i < 8; i++) {
                float p0 = __builtin_amdgcn_rcpf(1.0f + __expf(-st[2 * i]));
                float p1 = __builtin_amdgcn_rcpf(1.0f + __expf(-st[2 * i + 1]));
                dsum += p0 + p1;
                union { __bf16 h[2]; uint32_t u; } pk;
                pk.h[0] = (__bf16)p0;
                pk.h[1] = (__bf16)p1;
                wv[i] = pk.u;
            }
            if (inA) dA += dsum;
            if (inB) dB += dsum;

            // P relayout via permlane32_swap: ret[0]={x.lo|y.lo}, ret[1]={x.hi|y.hi}
            u32x2 rA = __builtin_amdgcn_permlane32_swap(wv[0], wv[2], false, false);
            u32x2 rB = __builtin_amdgcn_permlane32_swap(wv[1], wv[3], false, false);
            u32x2 rC = __builtin_amdgcn_permlane32_swap(wv[4], wv[6], false, false);
            u32x2 rD = __builtin_amdgcn_permlane32_swap(wv[5], wv[7], false, false);
            union { uint32_t u[4]; bf16x8 v; } A0, A1;
            A0.u[0] = rA[0]; A0.u[1] = rB[0]; A0.u[2] = rA[1]; A0.u[3] = rB[1];
            A1.u[0] = rC[0]; A1.u[1] = rD[0]; A1.u[2] = rC[1]; A1.u[3] = rD[1];

            const int ko = kt * 64 + h5 * 16;
            bf16x8 v00 = *(const bf16x8*)(vb + l31 * VTS + ko);
            bf16x8 v01 = *(const bf16x8*)(vb + l31 * VTS + ko + 32);
            bf16x8 v10 = *(const bf16x8*)(vb + (32 + l31) * VTS + ko);
            bf16x8 v11 = *(const bf16x8*)(vb + (32 + l31) * VTS + ko + 32);

            if (inA) {
                accA0 = __builtin_amdgcn_mfma_f32_32x32x16_bf16(A0.v, v00, accA0, 0, 0, 0);
                accA0 = __builtin_amdgcn_mfma_f32_32x32x16_bf16(A1.v, v01, accA0, 0, 0, 0);
                accA1 = __builtin_amdgcn_mfma_f32_32x32x16_bf16(A0.v, v10, accA1, 0, 0, 0);
                accA1 = __builtin_amdgcn_mfma_f32_32x32x16_bf16(A1.v, v11, accA1, 0, 0, 0);
            }
            if (inB) {
                accB0 = __builtin_amdgcn_mfma_f32_32x32x16_bf16(A0.v, v00, accB0, 0, 0, 0);
                accB0 = __builtin_amdgcn_mfma_f32_32x32x16_bf16(A1.v, v01, accB0, 0, 0, 0);
                accB1 = __builtin_amdgcn_mfma_f32_32x32x16_bf16(A0.v, v10, accB1, 0, 0, 0);
                accB1 = __builtin_amdgcn_mfma_f32_32x32x16_bf16(A1.v, v11, accB1, 0, 0, 0);
            }
        }
    }

    // ---- epilogue
    const float dAt = dA + __shfl_xor(dA, 32, 64);
    const float dBt = dB + __shfl_xor(dB, 32, 64);
    const float invA = __builtin_amdgcn_rcpf(dAt);
    const float invB = __builtin_amdgcn_rcpf(dBt);

#pragma unroll
    for (int r = 0; r < 16; r++) {
        const int cr = (r & 3) + 8 * (r >> 2) + 4 * h5;
        const int j  = w * 32 + cr;
        const float ia = __shfl(invA, cr, 64);
        const float ib = __shfl(invB, cr, 64);
        float o0, o1;
        if (m == 0) {
            o0 = accB0[r] * ib;
            o1 = accB1[r] * ib;
        } else {
            const float alpha = (float)j * (1.0f / 255.0f);
            o0 = (1.0f - alpha) * (accA0[r] * ia) + alpha * (accB0[r] * ib);
            o1 = (1.0f - alpha) * (accA1[r] * ia) + alpha * (accB1[r] * ib);
        }
        float* orow = Ob + (size_t)(m * QB + j) * DD;
        orow[l31]      = o0;
        orow[32 + l31] = o1;
    }
}

// ---- fallback (ws too small): round-2-verified structure, K/V from f32.
__global__ void __launch_bounds__(512, 2)
swa_fb_kernel(const float* __restrict__ Q, const float* __restrict__ K,
              const float* __restrict__ V, const float* __restrict__ scale_p,
              float* __restrict__ out)
{
    int lid = (int)blockIdx.x;
    lid = (lid & 7) * 64 + (lid >> 3);
    const int m  = lid & 15;
    const int bh = lid >> 4;

    const float scale = scale_p[0];
    const float* Qb = Q + (size_t)bh * SEQ * DD;
    const float* Kb = K + (size_t)bh * SEQ * DD;
    const float* Vb = V + (size_t)bh * SEQ * DD;
    float*       Ob = out + (size_t)bh * SEQ * DD;

    const int tid  = threadIdx.x;
    const int lane = tid & 63;
    const int w    = tid >> 6;
    const int l31  = lane & 31;
    const int h5   = lane >> 5;

    __shared__ __align__(16) unsigned char vt[64 * VSTR];

    bf16x8 qf[4];
    {
        const float* qp = Qb + (size_t)(m * QB + w * 32 + l31) * DD + 8 * h5;
#pragma unroll
        for (int s = 0; s < 4; s++) {
            float4 a = *(const float4*)(qp + 16 * s);
            float4 b = *(const float4*)(qp + 16 * s + 4);
            bf16x8 f;
            f[0] = (__bf16)(a.x * scale); f[1] = (__bf16)(a.y * scale);
            f[2] = (__bf16)(a.z * scale); f[3] = (__bf16)(a.w * scale);
            f[4] = (__bf16)(b.x * scale); f[5] = (__bf16)(b.y * scale);
            f[6] = (__bf16)(b.z * scale); f[7] = (__bf16)(b.w * scale);
            qf[s] = f;
        }
    }

    f32x16 accA0 = zero16(), accA1 = zero16();
    f32x16 accB0 = zero16(), accB1 = zero16();
    float dA = 0.0f, dB = 0.0f;

    for (int ci = 0; ci < 3; ci++) {
        const int ck = (m - 1 + ci) * CH;
        if (ck < 0 || ck >= SEQ) continue;
        const bool inA = (m > 0) && (ci <= 1);
        const bool inB = (ci >= 1);

        __syncthreads();
        {
            const int kk = (tid & 127) * 2;
            const int dg = tid >> 7;
            const float* vp0 = Vb + (size_t)(ck + kk) * DD + dg * 16;
            const float* vp1 = vp0 + DD;
#pragma unroll
            for (int j = 0; j < 16; j += 4) {
                float4 a = *(const float4*)(vp0 + j);
                float4 b = *(const float4*)(vp1 + j);
                float av[4] = {a.x, a.y, a.z, a.w};
                float bv[4] = {b.x, b.y, b.z, b.w};
#pragma unroll
                for (int e = 0; e < 4; e++) {
                    union { __bf16 h[2]; uint32_t u; } pk;
                    pk.h[0] = (__bf16)av[e];
                    pk.h[1] = (__bf16)bv[e];
                    *(uint32_t*)(vt + (size_t)(dg * 16 + j + e) * VSTR + kk * 2) = pk.u;
                }
            }
        }
        __syncthreads();

        for (int kt = 0; kt < 8; kt++) {
            const float* kp = Kb + (size_t)(ck + kt * 32 + l31) * DD + 8 * h5;
            f32x16 st = zero16();
#pragma unroll
            for (int s = 0; s < 4; s++) {
                float4 a = *(const float4*)(kp + 16 * s);
                float4 b = *(const float4*)(kp + 16 * s + 4);
                bf16x8 f;
                f[0] = (__bf16)a.x; f[1] = (__bf16)a.y; f[2] = (__bf16)a.z; f[3] = (__bf16)a.w;
                f[4] = (__bf16)b.x; f[5] = (__bf16)b.y; f[6] = (__bf16)b.z; f[7] = (__bf16)b.w;
                st = __builtin_amdgcn_mfma_f32_32x32x16_bf16(f, qf[s], st, 0, 0, 0);
            }

            uint32_t wv[8];
            float dsum = 0.0f;
#pragma unroll
            for (int i = 0; i < 8; i++) {
                float p0 = __builtin_amdgcn_rcpf(1.0f + __expf(-st[2 * i]));
                float p1 = __builtin_amdgcn_rcpf(1.0f + __expf(-st[2 * i + 1]));
                dsum += p0 + p1;
                union { __bf16 h[2]; uint32_t u; } pk;
                pk.h[0] = (__bf16)p0;
                pk.h[1] = (__bf16)p1;
                wv[i] = pk.u;
            }
            if (inA) dA += dsum;
            if (inB) dB += dsum;

            u32x2 rA = __builtin_amdgcn_permlane32_swap(wv[0], wv[2], false, false);
            u32x2 rB = __builtin_amdgcn_permlane32_swap(wv[1], wv[3], false, false);
            u32x2 rC = __builtin_amdgcn_permlane32_swap(wv[4], wv[6], false, false);
            u32x2 rD = __builtin_amdgcn_permlane32_swap(wv[5], wv[7], false, false);
            union { uint32_t u[4]; bf16x8 v; } A0, A1;
            A0.u[0] = rA[0]; A0.u[1] = rB[0]; A0.u[2] = rA[1]; A0.u[3] = rB[1];
            A1.u[0] = rC[0]; A1.u[1] = rD[0]; A1.u[2] = rC[1]; A1.u[3] = rD[1];

            const unsigned char* vrow0 = vt + (size_t)l31 * VSTR;
            const unsigned char* vrow1 = vt + (size_t)(32 + l31) * VSTR;
            const int ko = kt * 64 + h5 * 16;
            bf16x8 v00 = *(const bf16x8*)(vrow0 + ko);
            bf16x8 v01 = *(const bf16x8*)(vrow0 + ko + 32);
            bf16x8 v10 = *(const bf16x8*)(vrow1 + ko);
            bf16x8 v11 = *(const bf16x8*)(vrow1 + ko + 32);

            if (inA) {
                accA0 = __builtin_amdgcn_mfma_f32_32x32x16_bf16(A0.v, v00, accA0, 0, 0, 0);
                accA0 = __builtin_amdgcn_mfma_f32_32x32x16_bf16(A1.v, v01, accA0, 0, 0, 0);
                accA1 = __builtin_amdgcn_mfma_f32_32x32x16_bf16(A0.v, v10, accA1, 0, 0, 0);
                accA1 = __builtin_amdgcn_mfma_f32_32x32x16_bf16(A1.v, v11, accA1, 0, 0, 0);
            }
            if (inB) {
                accB0 = __builtin_amdgcn_mfma_f32_32x32x16_bf16(A0.v, v00, accB0, 0, 0, 0);
                accB0 = __builtin_amdgcn_mfma_f32_32x32x16_bf16(A1.v, v01, accB0, 0, 0, 0);
                accB1 = __builtin_amdgcn_mfma_f32_32x32x16_bf16(A0.v, v10, accB1, 0, 0, 0);
                accB1 = __builtin_amdgcn_mfma_f32_32x32x16_bf16(A1.v, v11, accB1, 0, 0, 0);
            }
        }
    }

    const float dAt = dA + __shfl_xor(dA, 32, 64);
    const float dBt = dB + __shfl_xor(dB, 32, 64);
    const float invA = __builtin_amdgcn_rcpf(dAt);
    const float invB = __builtin_amdgcn_rcpf(dBt);

#pragma unroll
    for (int r = 0; r < 16; r++) {
        const int cr = (r & 3) + 8 * (r >> 2) + 4 * h5;
        const int j  = w * 32 + cr;
        const float ia = __shfl(invA, cr, 64);
        const float ib = __shfl(invB, cr, 64);
        float o0, o1;
        if (m == 0) {
            o0 = accB0[r] * ib;
            o1 = accB1[r] * ib;
        } else {
            const float alpha = (float)j * (1.0f / 255.0f);
            o0 = (1.0f - alpha) * (accA0[r] * ia) + alpha * (accB0[r] * ib);
            o1 = (1.0f - alpha) * (accA1[r] * ia) + alpha * (accB1[r] * ib);
        }
        float* orow = Ob + (size_t)(m * QB + j) * DD;
        orow[l31]      = o0;
        orow[32 + l31] = o1;
    }
}

extern "C" void kernel_launch(void* const* d_in, const int* in_sizes, int n_in,
                              void* d_out, int out_size, void* d_ws, size_t ws_size,
                              hipStream_t stream) {
    const float* Q = (const float*)d_in[0];
    const float* K = (const float*)d_in[1];
    const float* V = (const float*)d_in[2];
    const float* s = (const float*)d_in[3];
    float* out = (float*)d_out;

    const size_t halfBytes = (size_t)NB * NH * SEQ * DD * 2;   // 16.8 MB (bf16)
    dim3 grid(NB * NH * NM, 1, 1);                             // 512
    dim3 block(512, 1, 1);

    if (ws_size >= 2 * halfBytes) {
        unsigned char* kw = (unsigned char*)d_ws;
        unsigned char* vw = kw + halfBytes;
        dim3 cgk((unsigned)((size_t)NB * NH * SEQ * 4 / 256), 1, 1);   // 2048
        dim3 cgv((unsigned)((size_t)NB * NH * SEQ / 64), 1, 1);        // 8192
        hipLaunchKernelGGL(cvt_k_kernel, cgk, dim3(256, 1, 1), 0, stream, K, kw);
        hipLaunchKernelGGL(cvt_v_kernel, cgv, dim3(256, 1, 1), 0, stream, V, vw);
        hipLaunchKernelGGL(swa_pre_kernel, grid, block, 0, stream, Q, s, kw, vw, out);
    } else {
        hipLaunchKernelGGL(swa_fb_kernel, grid, block, 0, stream, Q, K, V, s, out);
    }
}